// Round 1
// baseline (76.576 us; speedup 1.0000x reference)
//
#include <hip/hip_runtime.h>
#include <math.h>

// Problem constants
#define NQ 10
#define DIM 1024          // 2^10
#define NPTS 64
#define DFEAT 10
#define NLAYERS 5
#define NPAIR 2080        // 64*65/2 upper-triangle pairs
#define GBLK  (NPAIR / 4) // 520 gram blocks, 4 waves each

#define IS2 0.70710678118654752440f

// ws layout: psi (64*1024 float2 = 512 KB) | partials (2*GBLK floats)
#define PART_OFF ((size_t)NPTS * DIM * sizeof(float2))

// ---------------------------------------------------------------------------
// Kernel 1: psi_i = U(x_i)|0>. 1024 threads (16 waves) per block, 64 blocks.
// One amplitude per thread.
//
// R4 lesson: keep loops ROLLED (unrolled version was I-fetch bound).
// R6 lesson: no single-address device atomics.
// R7 change (this round): BIT-GROUP TRANSPOSE. The old version did 4 LDS
// exchange round-trips (8 barriers) per layer for qubits 6..9. Now we do ONE
// LDS permutation per layer that swaps amplitude bits 0-3 <-> 6-9 (sigma),
// after which qubits 6..9 are LANE bits and every gate is a shfl_xor
// butterfly. Odd layers run entirely in the sigma basis (1 transpose/layer,
// alternating), layer 4 exits in the identity basis -> coalesced psi write.
// Barriers per block: 32 -> 8. LDS round-trips: 16 -> 4.
//
// LDS swizzle: reading xbuf[sigma(t)] from a linear layout puts ALL 64 lanes
// on banks 0-1 (sigma strides 64 and 16 float2 -> 512B/128B, both = bank 0
// mod 32). Store at swz(a) = a ^ ((a>>6)&0xF): within a wave both the write
// index (swz of held-amp index) and the read index (swz of wanted-amp index)
// are bijections of lane onto 0..63 -> conflict-free (minimal 8B aliasing).
//
// Verified algebra (absmax==0 in R4-R6):
//  - fused 1q gate M = RY(t)*RZ(x)*H; x angle is x[9-q] every layer.
//    cx=cos(x/2), sx=sin(x/2), c=cos(t/2), s=sin(t/2), p=(c+s)/sqrt2,
//    q=(c-s)/sqrt2:  m00=(q*cx,-p*sx) m01=(p*cx,-q*sx)
//                    m10=(p*cx, q*sx) m11=(-q*cx,-p*sx)   (store m00,m01)
//  - layer 0 acts on |0> -> product state (no exchanges)
//  - layer 5 ring diag + RY are data-independent outer unitaries -> cancel
//    in |<psi_j|psi_i>|^2 (c=1,s=0; ring skipped)
//  - single-qubit gates on distinct qubits commute -> per-layer qubit order
//    (4,5,6..9,0..3 on sigma-entry layers) only reassociates fp rounding.
// ---------------------------------------------------------------------------
__device__ __forceinline__ void ring_rot(float& re, float& im,
                                         const float* __restrict__ rg,
                                         int idx)
{
    float ph = 0.f;
#pragma unroll 1
    for (int n = 0; n < NQ; ++n) {
        const int   nn = (n == 9) ? 0 : (n + 1);
        const float g  = rg[n];     // wave-uniform -> s_load
        const float t  = (((idx >> nn) & 1) ? 0.5f : -0.5f) * g;
        ph += ((idx >> n) & 1) ? t : 0.f;
    }
    const float s = __sinf(ph), c = __cosf(ph);
    const float nr = re * c - im * s;
    const float ni = re * s + im * c;
    re = nr; im = ni;
}

__global__ __launch_bounds__(1024) void state_kernel(
    const float* __restrict__ data,     // (64,10)
    const float* __restrict__ params,   // (5,2,10)
    float2* __restrict__ psi)           // (64,1024)
{
    const int i    = blockIdx.x;
    const int tid  = threadIdx.x;

    __shared__ float4 mc[NLAYERS][NQ];   // (m00r, m00i, m01r, m01i)
    __shared__ float2 xbuf[DIM];         // transpose buffer (8 KB)

    // sigma: swap amplitude bits 0-3 <-> 6-9 (bits 4,5 fixed). Involution.
    const int sig    = (tid & 0x030) | ((tid & 0x00F) << 6) | ((tid >> 6) & 0x00F);
    const int aw_id  = tid ^ ((tid >> 6) & 0xF);   // swz(tid)
    const int aw_sig = sig ^ (tid & 0xF);          // swz(sig): (sig>>6)&0xF == tid&0xF

    // ---- precompute fused gate coefficients (50 threads, once) ----
    if (tid < NLAYERS * NQ) {
        const int L = tid / NQ, q = tid - L * NQ;
        const float xh = 0.5f * data[i * DFEAT + (9 - q)];
        const float cx = __cosf(xh), sx = __sinf(xh);
        float c = 1.f, s = 0.f;
        if (L != NLAYERS - 1) {
            const float th = 0.5f * params[L * 2 * NQ + q];
            c = __cosf(th); s = __sinf(th);
        }
        const float p = (c + s) * IS2, qm = (c - s) * IS2;
        mc[L][q] = make_float4(qm * cx, -p * sx, p * cx, -qm * sx);
    }
    __syncthreads();

    // ---- layer 0: product state (pi = id) ----
    float re, im;
    {
        float Pr = 1.f, Pi = 0.f;
#pragma unroll 1
        for (int q = 0; q < NQ; ++q) {
            const float4 m = mc[0][q];
            const int b = (tid >> q) & 1;
            const float fr = b ? m.z : m.x;      // u1 = m10, u0 = m00
            const float fi = b ? -m.w : m.y;
            const float nr = Pr * fr - Pi * fi;
            const float ni = Pr * fi + Pi * fr;
            Pr = nr; Pi = ni;
        }
        re = Pr; im = Pi;
    }
    // ring of layer 0 (pi = id)
    ring_rot(re, im, params + NQ, tid);

    // ---- layers 1..4: 10 shfl butterflies + 1 transpose per layer ----
    // entry basis: L odd -> id (ph=0), L even -> sigma (ph=1)
#pragma unroll 1
    for (int L = 1; L < NLAYERS; ++L) {
        const int ph = (L - 1) & 1;
#pragma unroll 1
        for (int s = 0; s < NQ; ++s) {
            if (s == 6) {
                // transpose: ph=0: id->sigma, ph=1: sigma->id
                xbuf[ph ? aw_sig : aw_id] = make_float2(re, im);
                __syncthreads();
                const float2 v = xbuf[ph ? aw_id : aw_sig];
                re = v.x; im = v.y;
                __syncthreads();
            }
            int q, lb;
            if (ph == 0) { q = s;                      lb = (s < 6) ? s : s - 6; }
            else         { q = (s < 6) ? s + 4 : s - 6; lb = (q >= 6) ? q - 6 : q; }
            const float4 m = mc[L][q];
            const int   b = (tid >> lb) & 1;           // amp bit q == thread bit lb
            const float msr = b ? -m.x : m.x;          // m11r / m00r
            const float msi = m.y;                     // m11i == m00i
            const float mpr = m.z;                     // m10r == m01r
            const float mpi = b ? -m.w : m.w;          // m10i / m01i
            const float pr = __shfl_xor(re, 1 << lb, 64);
            const float pi = __shfl_xor(im, 1 << lb, 64);
            const float nr = msr * re - msi * im + mpr * pr - mpi * pi;
            const float ni = msr * im + msi * re + mpr * pi + mpi * pr;
            re = nr; im = ni;
        }
        // ring diagonal (skip layer 4: cancels). Exit basis: ph=0 -> sigma.
        if (L < NLAYERS - 1) {
            ring_rot(re, im, params + L * 2 * NQ + NQ, (ph == 0) ? sig : tid);
        }
    }

    // loop ends after L=4 (entered sigma, exited id) -> coalesced write
    psi[i * DIM + tid] = make_float2(re, im);
}

// ---------------------------------------------------------------------------
// Kernel 2: gram partials over the UPPER TRIANGLE only. (unchanged)
// ---------------------------------------------------------------------------
__global__ __launch_bounds__(256) void gram_kernel(
    const float4* __restrict__ psi4,    // (64, 512) float4 view of psi
    const float* __restrict__ labels,   // (64,)
    float* __restrict__ partials)       // (2*GBLK,)
{
    __shared__ float sm[2][4];
    const int wave = threadIdx.x >> 6;
    const int lane = threadIdx.x & 63;
    const int w    = blockIdx.x * 4 + wave;   // 0..2079

    // triangle index: i = row with C(i) = 64i - i(i-1)/2 <= w < C(i+1)
    int i = (int)((129.0f - sqrtf(16641.0f - 8.0f * (float)w)) * 0.5f);
    int Ci = 64 * i - ((i * (i - 1)) >> 1);
    while (w < Ci)            { --i; Ci = 64 * i - ((i * (i - 1)) >> 1); }
    while (w >= Ci + 64 - i)  { Ci += 64 - i; ++i; }
    const int j = i + (w - Ci);

    const float4* a = psi4 + i * (DIM / 2);
    const float4* b = psi4 + j * (DIM / 2);

    float zr = 0.f, zi = 0.f;   // <psi_j|psi_i> = sum conj(b)*a
#pragma unroll
    for (int r = 0; r < 8; ++r) {
        const int k = (r << 6) | lane;
        const float4 av = a[k], bv = b[k];
        zr += bv.x * av.x + bv.y * av.y + bv.z * av.z + bv.w * av.w;
        zi += bv.x * av.y - bv.y * av.x + bv.z * av.w - bv.w * av.z;
    }
#pragma unroll
    for (int off = 32; off; off >>= 1) {
        zr += __shfl_xor(zr, off, 64);
        zi += __shfl_xor(zi, off, 64);
    }

    if (lane == 0) {
        const float k = zr * zr + zi * zi;
        const float wgt = (i == j) ? 1.f : 2.f;
        sm[0][wave] = wgt * labels[i] * labels[j] * k;
        sm[1][wave] = wgt * k * k;
    }
    __syncthreads();
    if (threadIdx.x == 0) {
        partials[2 * blockIdx.x]     = sm[0][0] + sm[0][1] + sm[0][2] + sm[0][3];
        partials[2 * blockIdx.x + 1] = sm[1][0] + sm[1][1] + sm[1][2] + sm[1][3];
    }
}

// ---------------------------------------------------------------------------
// Kernel 3: final KTA. (unchanged)
// ---------------------------------------------------------------------------
__global__ __launch_bounds__(256) void reduce_kernel(
    const float* __restrict__ partials,
    const float* __restrict__ labels,
    float* __restrict__ out)
{
    __shared__ float sm[3][4];
    const int tid  = threadIdx.x;
    const int lane = tid & 63;
    const int wave = tid >> 6;

    float slk = 0.f, skk = 0.f, sl2 = 0.f;
    for (int p = tid; p < GBLK; p += 256) {
        slk += partials[2 * p];
        skk += partials[2 * p + 1];
    }
    if (tid < NPTS) { const float l = labels[tid]; sl2 = l * l; }

#pragma unroll
    for (int off = 32; off; off >>= 1) {
        slk += __shfl_xor(slk, off, 64);
        skk += __shfl_xor(skk, off, 64);
        sl2 += __shfl_xor(sl2, off, 64);
    }
    if (lane == 0) { sm[0][wave] = slk; sm[1][wave] = skk; sm[2][wave] = sl2; }
    __syncthreads();
    if (tid == 0) {
        const float a = sm[0][0] + sm[0][1] + sm[0][2] + sm[0][3];
        const float b = sm[1][0] + sm[1][1] + sm[1][2] + sm[1][3];
        const float c = sm[2][0] + sm[2][1] + sm[2][2] + sm[2][3];
        out[0] = a / sqrtf(b * (c * c));
    }
}

extern "C" void kernel_launch(void* const* d_in, const int* in_sizes, int n_in,
                              void* d_out, int out_size, void* d_ws, size_t ws_size,
                              hipStream_t stream) {
    const float* data   = (const float*)d_in[0];  // (64,10)
    const float* labels = (const float*)d_in[1];  // (64,)
    const float* params = (const float*)d_in[2];  // (5,2,10)
    float* out = (float*)d_out;

    float2* psi      = (float2*)d_ws;
    float*  partials = (float*)((char*)d_ws + PART_OFF);

    state_kernel <<<NPTS, 1024, 0, stream>>>(data, params, psi);
    gram_kernel  <<<GBLK,  256, 0, stream>>>((const float4*)psi, labels, partials);
    reduce_kernel<<<1,     256, 0, stream>>>(partials, labels, out);
}